// Round 1
// baseline (622.324 us; speedup 1.0000x reference)
//
#include <hip/hip_runtime.h>
#include <math.h>

// Problem constants
#define B_    1024
#define D_    512
#define V_    100000
#define NP_   100096            // padded V (782 tiles * 128)
#define NT_   782
#define EPS_  1e-7f
#define COSM  0.9210609940028851f   // cos(0.4)
#define SINM  0.3894183423086505f   // sin(0.4)

typedef __bf16 bf16x8 __attribute__((ext_vector_type(8)));
typedef float  f32x4  __attribute__((ext_vector_type(4)));

struct alignas(16) US8 { unsigned short h[8]; };

// round-to-nearest-even float -> bf16 bits (inputs finite)
__device__ __forceinline__ unsigned short f2bf(float f) {
  union { float f; unsigned u; } a; a.f = f;
  unsigned u = a.u;
  u += 0x7FFFu + ((u >> 16) & 1u);
  return (unsigned short)(u >> 16);
}

__device__ __forceinline__ void async_copy16(void* lds, const void* g) {
  __builtin_amdgcn_global_load_lds(
      (const __attribute__((address_space(1))) void*)g,
      (__attribute__((address_space(3))) void*)lds, 16, 0, 0);
}

// ---------------------------------------------------------------------------
// Kernel 1: L2-normalize rows of x -> bf16; zero S.
// grid 256 x block 256 (4 waves = 4 rows per block)
// ---------------------------------------------------------------------------
__global__ void x_prep(const float* __restrict__ x,
                       unsigned short* __restrict__ xb,
                       float* __restrict__ S) {
  int t = threadIdx.x;
  int lane = t & 63, wave = t >> 6;
  int row = blockIdx.x * 4 + wave;
  const float* xr = x + (size_t)row * D_;
  f32x4 a = *(const f32x4*)(xr + lane * 8);
  f32x4 b = *(const f32x4*)(xr + lane * 8 + 4);
  float ss = a[0]*a[0] + a[1]*a[1] + a[2]*a[2] + a[3]*a[3]
           + b[0]*b[0] + b[1]*b[1] + b[2]*b[2] + b[3]*b[3];
#pragma unroll
  for (int off = 32; off > 0; off >>= 1) ss += __shfl_xor(ss, off, 64);
  float inv = 1.0f / fmaxf(sqrtf(ss), 1e-12f);
  US8 pk;
#pragma unroll
  for (int j = 0; j < 4; ++j) pk.h[j]     = f2bf(a[j] * inv);
#pragma unroll
  for (int j = 0; j < 4; ++j) pk.h[4 + j] = f2bf(b[j] * inv);
  *(US8*)(xb + (size_t)row * D_ + lane * 8) = pk;
  if (lane == 0) S[row] = 0.0f;
}

// ---------------------------------------------------------------------------
// Kernel 1b (NEW): convert w (fp32 row-major [D][V]) once to bf16 TRANSPOSED
// wbT [NP][D] (column-major along K), accumulating per-column sum-of-squares
// into wssq via atomics. Memory-bound (~307 MB traffic); the f2bf VALU work
// hides under it, and it runs ONCE instead of once per m-tile (8x) inside
// the GEMM. grid (98, 8) x block 256: block = 1024 cols x 64 rows.
// ---------------------------------------------------------------------------
__global__ __launch_bounds__(256) void w_prep(const float* __restrict__ w,
                                              unsigned short* __restrict__ wbT,
                                              float* __restrict__ wssq) {
  int t  = threadIdx.x;
  int c0 = blockIdx.x * 1024 + t * 4;
  int r0 = blockIdx.y * 64;
  bool valid = (c0 + 3) < V_;   // all-or-nothing (V_ % 4 == 0)
  if (valid) {
    const float* src = w + (size_t)r0 * V_ + c0;
    float ssq[4] = {0.0f, 0.0f, 0.0f, 0.0f};
    for (int rr = 0; rr < 64; rr += 8) {
      US8 out[4];
#pragma unroll
      for (int i = 0; i < 8; ++i) {
        f32x4 v = *(const f32x4*)(src + (size_t)(rr + i) * V_);
#pragma unroll
        for (int cc = 0; cc < 4; ++cc) {
          ssq[cc] += v[cc] * v[cc];
          out[cc].h[i] = f2bf(v[cc]);
        }
      }
#pragma unroll
      for (int cc = 0; cc < 4; ++cc)
        *(US8*)(wbT + (size_t)(c0 + cc) * D_ + r0 + rr) = out[cc];
    }
#pragma unroll
    for (int cc = 0; cc < 4; ++cc) atomicAdd(&wssq[c0 + cc], ssq[cc]);
  } else if (c0 < NP_) {        // zero the pad columns so GEMM DMA reads 0
    US8 z = {};
    for (int rr = 0; rr < 64; rr += 8)
#pragma unroll
      for (int cc = 0; cc < 4; ++cc)
        *(US8*)(wbT + (size_t)(c0 + cc) * D_ + r0 + rr) = z;
  }
}

// ---------------------------------------------------------------------------
// Kernel 2 (NEW): pure-bf16 128x128 MFMA GEMM, m97 structure on BOTH
// operands: A from xb, B from wbT, each via global_load_lds width=16 with
// pre-swizzled global source + linear LDS dest. No per-iter VALU convert,
// no ds_writes (kills the 1.9e7 bank conflicts). Fused ArcFace epilogue
// with column inv-norms from precomputed wssq.
// grid 6272 x block 256 (4 waves, 2x2 of 64x64). XCD-aware block mapping.
// ---------------------------------------------------------------------------
#define BM 128
#define BN 128
#define BK 64

__global__ __launch_bounds__(256) void gemm_fused_dma(
    const unsigned short* __restrict__ xb,
    const unsigned short* __restrict__ wbT,
    const float* __restrict__ wssq,
    const int* __restrict__ labels,
    float* __restrict__ S, float* __restrict__ Lb) {
  int bid = blockIdx.x;
  int xcd = bid & 7;
  int slot = bid >> 3;          // 0..783
  int tn = xcd * 98 + (slot >> 3);
  int tm = slot & 7;
  if (tn >= NT_) return;
  int m0 = tm * BM, n0 = tn * BN;

  // LDS slot p (16B chunks) holds (m = p>>3, kc = (p&7) ^ (m&7))
  __shared__ unsigned short Ab[BM * BK];  // 16 KB
  __shared__ unsigned short Bb[BN * BK];  // 16 KB
  __shared__ int labT[BM];
  int t = threadIdx.x;
  if (t < BM) labT[t] = labels[m0 + t];
  int lane = t & 63;
  int q = lane >> 4, l15 = lane & 15;
  int wave = t >> 6;
  int wm = (wave & 1) * 64, wn = (wave >> 1) * 64;
  f32x4 acc[4][4] = {};

  // ---- staging addresses: pre-swizzled global src, linear LDS dest ----
  const unsigned short* gA[4]; unsigned short* lA[4];
  const unsigned short* gB[4]; unsigned short* lB[4];
#pragma unroll
  for (int j = 0; j < 4; ++j) {
    int p = t + 256 * j;
    int m = p >> 3;
    int kc = (p & 7) ^ (m & 7);
    gA[j] = xb  + (size_t)(m0 + m) * D_ + kc * 8;
    lA[j] = Ab + p * 8;
    gB[j] = wbT + (size_t)(n0 + m) * D_ + kc * 8;   // wbT is [col][K]
    lB[j] = Bb + p * 8;
  }

  for (int kt = 0; kt < D_; kt += BK) {
#pragma unroll
    for (int j = 0; j < 4; ++j) async_copy16(lA[j], gA[j] + kt);
#pragma unroll
    for (int j = 0; j < 4; ++j) async_copy16(lB[j], gB[j] + kt);
    __syncthreads();            // compiler drains vmcnt before s_barrier

    int h = l15 & 7;
#pragma unroll
    for (int s = 0; s < 2; ++s) {
      int kx = s * 4 + q;
      bf16x8 af[4], bfr[4];
#pragma unroll
      for (int ri = 0; ri < 4; ++ri) {
        int row_ = wm + ri * 16 + l15;
        af[ri] = *(const bf16x8*)&Ab[(row_ * 8 + (kx ^ h)) * 8];
      }
#pragma unroll
      for (int ci = 0; ci < 4; ++ci) {
        int row_ = wn + ci * 16 + l15;
        bfr[ci] = *(const bf16x8*)&Bb[(row_ * 8 + (kx ^ h)) * 8];
      }
#pragma unroll
      for (int ri = 0; ri < 4; ++ri)
#pragma unroll
        for (int ci = 0; ci < 4; ++ci)
          acc[ri][ci] = __builtin_amdgcn_mfma_f32_16x16x32_bf16(
              af[ri], bfr[ci], acc[ri][ci], 0, 0, 0);
    }
    __syncthreads();
  }

  // ---- epilogue: C/D layout col = lane&15 (n side), row = q*4 + reg ----
  float iw[4]; int vcol[4];
#pragma unroll
  for (int ci = 0; ci < 4; ++ci) {
    int nl = wn + ci * 16 + l15;
    vcol[ci] = n0 + nl;
    iw[ci] = (vcol[ci] < V_) ? 1.0f / fmaxf(sqrtf(wssq[vcol[ci]]), 1e-12f)
                             : 0.0f;
  }
#pragma unroll
  for (int ri = 0; ri < 4; ++ri) {
#pragma unroll
    for (int reg = 0; reg < 4; ++reg) {
      int ml = wm + ri * 16 + q * 4 + reg;
      int r = m0 + ml;
      int lab = labT[ml];
      float s = 0.0f;
#pragma unroll
      for (int ci = 0; ci < 4; ++ci) {
        float cv = acc[ri][ci][reg] * iw[ci];
        cv = fminf(fmaxf(cv, -1.0f + EPS_), 1.0f - EPS_);
        float logit = cv;
        if (vcol[ci] == lab) {
          logit = cv * COSM - sqrtf(fmaxf(1.0f - cv * cv, 0.0f)) * SINM;
          Lb[r] = logit;               // unique writer across grid
        }
        s += (vcol[ci] < V_) ? __expf(logit) : 0.0f;
      }
      s += __shfl_xor(s, 1, 64);
      s += __shfl_xor(s, 2, 64);
      s += __shfl_xor(s, 4, 64);
      s += __shfl_xor(s, 8, 64);
      if (l15 == 0) atomicAdd(&S[r], s);
    }
  }
}

// ---------------------------------------------------------------------------
// Kernel 2 FALLBACK (verbatim previous best): inline fp32->bf16 B-path.
// Used only if the workspace is too small for wbT.
// ---------------------------------------------------------------------------
__global__ __launch_bounds__(256) void gemm_fused_inline(
    const unsigned short* __restrict__ xb,
    const float* __restrict__ w,
    const int* __restrict__ labels,
    float* __restrict__ S, float* __restrict__ Lb) {
  int bid = blockIdx.x;
  int xcd = bid & 7;
  int slot = bid >> 3;
  int tn = xcd * 98 + (slot >> 3);
  int tm = slot & 7;
  if (tn >= NT_) return;
  int m0 = tm * BM, n0 = tn * BN;

  __shared__ unsigned short Ab[BM * BK];
  __shared__ unsigned short Bb[BN * BK];
  __shared__ float sqred[8][BN];
  __shared__ float iwL[BN];
  __shared__ int labT[BM];
  int t = threadIdx.x;
  if (t < BM) labT[t] = labels[m0 + t];
  int lane = t & 63;
  int q = lane >> 4, l15 = lane & 15;
  int wave = t >> 6;
  int wm = (wave & 1) * 64, wn = (wave >> 1) * 64;
  f32x4 acc[4][4] = {};

  const unsigned short* gA[4];
  unsigned short* lA[4];
#pragma unroll
  for (int j = 0; j < 4; ++j) {
    int p = t + 256 * j;
    int m = p >> 3;
    int kc = (p & 7) ^ (m & 7);
    gA[j] = xb + (size_t)(m0 + m) * D_ + kc * 8;
    lA[j] = Ab + p * 8;
  }

  int cg = t & 31;
  int rp = t >> 5;
  int c0l = cg * 4;
  bool vok = (n0 + c0l + 3) < V_;
  const float* wbase = w + (size_t)rp * 8 * V_ + n0 + c0l;
  unsigned short* bdst[4];
#pragma unroll
  for (int cc = 0; cc < 4; ++cc) {
    int col = c0l + cc;
    bdst[cc] = &Bb[(col * 8 + (rp ^ (col & 7))) * 8];
  }
  float ssq[4] = {0.0f, 0.0f, 0.0f, 0.0f};

  for (int kt = 0; kt < D_; kt += BK) {
#pragma unroll
    for (int j = 0; j < 4; ++j) async_copy16(lA[j], gA[j] + kt);

    f32x4 row[8];
    if (vok) {
#pragma unroll
      for (int i = 0; i < 8; ++i)
        row[i] = *(const f32x4*)(wbase + (size_t)i * V_);
    } else {
#pragma unroll
      for (int i = 0; i < 8; ++i) row[i] = f32x4{0.0f, 0.0f, 0.0f, 0.0f};
    }
#pragma unroll
    for (int cc = 0; cc < 4; ++cc) {
      US8 pk;
#pragma unroll
      for (int i = 0; i < 8; ++i) {
        float v = row[i][cc];
        ssq[cc] += v * v;
        pk.h[i] = f2bf(v);
      }
      *(US8*)bdst[cc] = pk;
    }
    wbase += (size_t)BK * V_;

    __syncthreads();
    int h = l15 & 7;
#pragma unroll
    for (int s = 0; s < 2; ++s) {
      int kx = s * 4 + q;
      bf16x8 af[4], bfr[4];
#pragma unroll
      for (int ri = 0; ri < 4; ++ri) {
        int row_ = wm + ri * 16 + l15;
        af[ri] = *(const bf16x8*)&Ab[(row_ * 8 + (kx ^ h)) * 8];
      }
#pragma unroll
      for (int ci = 0; ci < 4; ++ci) {
        int row_ = wn + ci * 16 + l15;
        bfr[ci] = *(const bf16x8*)&Bb[(row_ * 8 + (kx ^ h)) * 8];
      }
#pragma unroll
      for (int ri = 0; ri < 4; ++ri)
#pragma unroll
        for (int ci = 0; ci < 4; ++ci)
          acc[ri][ci] = __builtin_amdgcn_mfma_f32_16x16x32_bf16(
              af[ri], bfr[ci], acc[ri][ci], 0, 0, 0);
    }
    __syncthreads();
  }

#pragma unroll
  for (int cc = 0; cc < 4; ++cc) sqred[rp][c0l + cc] = ssq[cc];
  __syncthreads();
  if (t < BN) {
    float tot = 0.0f;
#pragma unroll
    for (int p = 0; p < 8; ++p) tot += sqred[p][t];
    iwL[t] = ((n0 + t) < V_) ? 1.0f / fmaxf(sqrtf(tot), 1e-12f) : 0.0f;
  }
  __syncthreads();

  float iw[4]; int vcol[4];
#pragma unroll
  for (int ci = 0; ci < 4; ++ci) {
    int nl = wn + ci * 16 + l15;
    vcol[ci] = n0 + nl;
    iw[ci] = iwL[nl];
  }
#pragma unroll
  for (int ri = 0; ri < 4; ++ri) {
#pragma unroll
    for (int reg = 0; reg < 4; ++reg) {
      int ml = wm + ri * 16 + q * 4 + reg;
      int r = m0 + ml;
      int lab = labT[ml];
      float s = 0.0f;
#pragma unroll
      for (int ci = 0; ci < 4; ++ci) {
        float cv = acc[ri][ci][reg] * iw[ci];
        cv = fminf(fmaxf(cv, -1.0f + EPS_), 1.0f - EPS_);
        float logit = cv;
        if (vcol[ci] == lab) {
          logit = cv * COSM - sqrtf(fmaxf(1.0f - cv * cv, 0.0f)) * SINM;
          Lb[r] = logit;
        }
        s += (vcol[ci] < V_) ? __expf(logit) : 0.0f;
      }
      s += __shfl_xor(s, 1, 64);
      s += __shfl_xor(s, 2, 64);
      s += __shfl_xor(s, 4, 64);
      s += __shfl_xor(s, 8, 64);
      if (l15 == 0) atomicAdd(&S[r], s);
    }
  }
}

// ---------------------------------------------------------------------------
// Kernel 3: loss = mean(log(S) - label_logit)
// ---------------------------------------------------------------------------
__global__ void finalk(const float* __restrict__ S, const float* __restrict__ Lb,
                       float* __restrict__ out) {
  __shared__ float red[256];
  int t = threadIdx.x;
  float s = 0.0f;
  for (int i = t; i < B_; i += 256) s += logf(S[i]) - Lb[i];
  red[t] = s;
  __syncthreads();
  for (int o = 128; o > 0; o >>= 1) {
    if (t < o) red[t] += red[t + o];
    __syncthreads();
  }
  if (t == 0) out[0] = red[0] * (1.0f / B_);
}

// ---------------------------------------------------------------------------
extern "C" void kernel_launch(void* const* d_in, const int* in_sizes, int n_in,
                              void* d_out, int out_size, void* d_ws, size_t ws_size,
                              hipStream_t stream) {
  const float* x = (const float*)d_in[0];
  const float* w = (const float*)d_in[1];
  const int* labels = (const int*)d_in[2];
  float* out = (float*)d_out;
  char* ws = (char*)d_ws;
  // ws layout (16B-aligned):
  //   xb   @ 0        : 1024*512 bf16            = 1,048,576 B
  //   S    @ 1048576  : 1024 f32                 =     4,096 B
  //   Lb   @ 1052672  : 1024 f32                 =     4,096 B
  //   wssq @ 1056768  : 100096 f32               =   400,384 B
  //   wbT  @ 1457152  : 100096*512 bf16 (transp) = 102,498,304 B
  unsigned short* xb = (unsigned short*)ws;
  float* S    = (float*)(ws + 1048576ull);
  float* Lb   = (float*)(ws + 1052672ull);
  float* wssq = (float*)(ws + 1056768ull);
  unsigned short* wbT = (unsigned short*)(ws + 1457152ull);
  const size_t WS_NEED = 1457152ull + (size_t)NP_ * D_ * 2ull;

  x_prep<<<256, 256, 0, stream>>>(x, xb, S);
  if (ws_size >= WS_NEED) {
    hipMemsetAsync(wssq, 0, (size_t)NP_ * sizeof(float), stream);
    w_prep<<<dim3(98, 8), 256, 0, stream>>>(w, wbT, wssq);
    gemm_fused_dma<<<6272, 256, 0, stream>>>(xb, wbT, wssq, labels, S, Lb);
  } else {
    gemm_fused_inline<<<6272, 256, 0, stream>>>(xb, w, labels, S, Lb);
  }
  finalk<<<1, 256, 0, stream>>>(S, Lb, out);
}

// Round 2
// 539.476 us; speedup vs baseline: 1.1536x; 1.1536x over previous
//
#include <hip/hip_runtime.h>
#include <math.h>

// Problem constants
#define B_    1024
#define D_    512
#define V_    100000
#define NP_   100096            // padded V (782 tiles * 128)
#define NT_   782
#define EPS_  1e-7f
#define COSM  0.9210609940028851f   // cos(0.4)
#define SINM  0.3894183423086505f   // sin(0.4)

typedef __bf16 bf16x8 __attribute__((ext_vector_type(8)));
typedef float  f32x4  __attribute__((ext_vector_type(4)));

struct alignas(16) US8 { unsigned short h[8]; };

// round-to-nearest-even float -> bf16 bits (inputs finite)
__device__ __forceinline__ unsigned short f2bf(float f) {
  union { float f; unsigned u; } a; a.f = f;
  unsigned u = a.u;
  u += 0x7FFFu + ((u >> 16) & 1u);
  return (unsigned short)(u >> 16);
}

__device__ __forceinline__ void async_copy16(void* lds, const void* g) {
  __builtin_amdgcn_global_load_lds(
      (const __attribute__((address_space(1))) void*)g,
      (__attribute__((address_space(3))) void*)lds, 16, 0, 0);
}

// ---------------------------------------------------------------------------
// Kernel 1: L2-normalize rows of x -> bf16; zero S.
// grid 256 x block 256 (4 waves = 4 rows per block)
// ---------------------------------------------------------------------------
__global__ void x_prep(const float* __restrict__ x,
                       unsigned short* __restrict__ xb,
                       float* __restrict__ S) {
  int t = threadIdx.x;
  int lane = t & 63, wave = t >> 6;
  int row = blockIdx.x * 4 + wave;
  const float* xr = x + (size_t)row * D_;
  f32x4 a = *(const f32x4*)(xr + lane * 8);
  f32x4 b = *(const f32x4*)(xr + lane * 8 + 4);
  float ss = a[0]*a[0] + a[1]*a[1] + a[2]*a[2] + a[3]*a[3]
           + b[0]*b[0] + b[1]*b[1] + b[2]*b[2] + b[3]*b[3];
#pragma unroll
  for (int off = 32; off > 0; off >>= 1) ss += __shfl_xor(ss, off, 64);
  float inv = 1.0f / fmaxf(sqrtf(ss), 1e-12f);
  US8 pk;
#pragma unroll
  for (int j = 0; j < 4; ++j) pk.h[j]     = f2bf(a[j] * inv);
#pragma unroll
  for (int j = 0; j < 4; ++j) pk.h[4 + j] = f2bf(b[j] * inv);
  *(US8*)(xb + (size_t)row * D_ + lane * 8) = pk;
  if (lane == 0) S[row] = 0.0f;
}

// ---------------------------------------------------------------------------
// Kernel 1b: w (fp32 row-major [D][V]) -> bf16 transposed wbT [NP][D], via
// LDS transpose so BOTH global sides are coalesced. Block = 64 cols x full K,
// K processed in 2 halves of 256 (T = 32 KB -> 4 blocks/CU).
// Per-column ssq is block-complete -> direct wssq store (no atomics/memset).
// grid 1564 x block 256.
// ---------------------------------------------------------------------------
#define WPC 64
#define KH  256

__global__ __launch_bounds__(256) void w_prep(const float* __restrict__ w,
                                              unsigned short* __restrict__ wbT,
                                              float* __restrict__ wssq) {
  __shared__ unsigned short T[WPC][KH];   // 32 KB, k-index XOR-swizzled
  __shared__ float sq[16][WPC];           // 4 KB
  int t = threadIdx.x;
  int c0 = blockIdx.x * WPC;
  int colv = (t & 15) * 4;                // column quad within block
  int rgrp = t >> 4;                      // 0..15
  int lane = t & 63, wave = t >> 6;
  bool vok = (c0 + colv + 3) < V_;        // per-quad validity (V_%4==0)
  float ssq[4] = {0.0f, 0.0f, 0.0f, 0.0f};

  for (int h = 0; h < 2; ++h) {
    // ---- phase 1: coalesced read, convert, transposed-swizzled LDS store
    if (vok) {
#pragma unroll
      for (int it = 0; it < 16; ++it) {
        int rl = rgrp + (it << 4);                   // 0..255
        int row = h * KH + rl;
        f32x4 v = *(const f32x4*)(w + (size_t)row * V_ + c0 + colv);
#pragma unroll
        for (int cc = 0; cc < 4; ++cc) {
          int col = colv + cc;
          ssq[cc] += v[cc] * v[cc];
          int f8 = ((col >> 2) & 7) << 3;
          T[col][rl ^ f8] = f2bf(v[cc]);
        }
      }
    } else {
#pragma unroll
      for (int it = 0; it < 16; ++it) {
        int rl = rgrp + (it << 4);
#pragma unroll
        for (int cc = 0; cc < 4; ++cc) {
          int col = colv + cc;
          int f8 = ((col >> 2) & 7) << 3;
          T[col][rl ^ f8] = 0;
        }
      }
    }
    __syncthreads();
    // ---- phase 2: coalesced global write. 2 cols per wave-instr,
    // lane&31 = 16B chunk within the column's 512B half-K run.
#pragma unroll
    for (int ci = 0; ci < 8; ++ci) {
      int col = wave * 16 + ci * 2 + (lane >> 5);
      int f = (col >> 2) & 7;
      int chunk = (lane & 31) ^ f;
      US8 pk = *(const US8*)&T[col][chunk * 8];
      *(US8*)(wbT + (size_t)(c0 + col) * D_ + h * KH + (lane & 31) * 8) = pk;
    }
    __syncthreads();   // T reused next half
  }

  // ---- column sum-of-squares: block-local reduce, direct store
#pragma unroll
  for (int cc = 0; cc < 4; ++cc) sq[rgrp][colv + cc] = ssq[cc];
  __syncthreads();
  if (t < WPC && (c0 + t) < V_) {
    float tot = 0.0f;
#pragma unroll
    for (int p = 0; p < 16; ++p) tot += sq[p][t];
    wssq[c0 + t] = tot;
  }
}

// ---------------------------------------------------------------------------
// Kernel 2: pure-bf16 128x128 MFMA GEMM, double-buffered LDS with
// prefetch-before-compute (minimal 2-phase, T3 recipe): stage tile k+1,
// then ds_read+MFMA tile k, then one vmcnt(0)+barrier. Fused ArcFace
// epilogue with precomputed wssq. grid 6272 x block 256.
// ---------------------------------------------------------------------------
#define BM 128
#define BN 128
#define BK 64
#define NKT (D_ / BK)

__global__ __launch_bounds__(256) void gemm_fused_dma(
    const unsigned short* __restrict__ xb,
    const unsigned short* __restrict__ wbT,
    const float* __restrict__ wssq,
    const int* __restrict__ labels,
    float* __restrict__ S, float* __restrict__ Lb) {
  int bid = blockIdx.x;
  int xcd = bid & 7;
  int slot = bid >> 3;          // 0..783
  int tn = xcd * 98 + (slot >> 3);
  int tm = slot & 7;
  if (tn >= NT_) return;
  int m0 = tm * BM, n0 = tn * BN;

  // LDS slot p (16B chunks) holds (m = p>>3, kc = (p&7) ^ (m&7))
  __shared__ unsigned short Ab[2][BM * BK];  // 2 x 16 KB
  __shared__ unsigned short Bb[2][BN * BK];  // 2 x 16 KB
  __shared__ int labT[BM];
  int t = threadIdx.x;
  if (t < BM) labT[t] = labels[m0 + t];
  int lane = t & 63;
  int q = lane >> 4, l15 = lane & 15;
  int wave = t >> 6;
  int wm = (wave & 1) * 64, wn = (wave >> 1) * 64;
  f32x4 acc[4][4] = {};

  // ---- staging addresses: pre-swizzled global src, linear LDS dest ----
  const unsigned short* gA[4]; unsigned short* lA[4];
  const unsigned short* gB[4]; unsigned short* lB[4];
#pragma unroll
  for (int j = 0; j < 4; ++j) {
    int p = t + 256 * j;
    int m = p >> 3;
    int kc = (p & 7) ^ (m & 7);
    gA[j] = xb  + (size_t)(m0 + m) * D_ + kc * 8;
    lA[j] = &Ab[0][p * 8];
    gB[j] = wbT + (size_t)(n0 + m) * D_ + kc * 8;   // wbT is [col][K]
    lB[j] = &Bb[0][p * 8];
  }

  // prologue: stage tile 0
#pragma unroll
  for (int j = 0; j < 4; ++j) async_copy16(lA[j], gA[j]);
#pragma unroll
  for (int j = 0; j < 4; ++j) async_copy16(lB[j], gB[j]);
  __syncthreads();

  int cur = 0;
  int h = l15 & 7;
  for (int kt = 0; kt < NKT; ++kt) {
    // prefetch next tile into the other buffer (latency hides under MFMA)
    if (kt + 1 < NKT) {
      int off = (cur ^ 1) * (BM * BK);
      int kk = (kt + 1) * BK;
#pragma unroll
      for (int j = 0; j < 4; ++j) async_copy16(lA[j] + off, gA[j] + kk);
#pragma unroll
      for (int j = 0; j < 4; ++j) async_copy16(lB[j] + off, gB[j] + kk);
    }
    const unsigned short* Ac = Ab[cur];
    const unsigned short* Bc = Bb[cur];
#pragma unroll
    for (int s = 0; s < 2; ++s) {
      int kx = s * 4 + q;
      bf16x8 af[4], bfr[4];
#pragma unroll
      for (int ri = 0; ri < 4; ++ri) {
        int row_ = wm + ri * 16 + l15;
        af[ri] = *(const bf16x8*)&Ac[(row_ * 8 + (kx ^ h)) * 8];
      }
#pragma unroll
      for (int ci = 0; ci < 4; ++ci) {
        int row_ = wn + ci * 16 + l15;
        bfr[ci] = *(const bf16x8*)&Bc[(row_ * 8 + (kx ^ h)) * 8];
      }
#pragma unroll
      for (int ri = 0; ri < 4; ++ri)
#pragma unroll
        for (int ci = 0; ci < 4; ++ci)
          acc[ri][ci] = __builtin_amdgcn_mfma_f32_16x16x32_bf16(
              af[ri], bfr[ci], acc[ri][ci], 0, 0, 0);
    }
    __syncthreads();   // drains vmcnt(0)+lgkmcnt(0): next buffer ready
    cur ^= 1;
  }

  // ---- epilogue: C/D layout col = lane&15 (n side), row = q*4 + reg ----
  float iw[4]; int vcol[4];
#pragma unroll
  for (int ci = 0; ci < 4; ++ci) {
    int nl = wn + ci * 16 + l15;
    vcol[ci] = n0 + nl;
    iw[ci] = (vcol[ci] < V_) ? 1.0f / fmaxf(sqrtf(wssq[vcol[ci]]), 1e-12f)
                             : 0.0f;
  }
#pragma unroll
  for (int ri = 0; ri < 4; ++ri) {
#pragma unroll
    for (int reg = 0; reg < 4; ++reg) {
      int ml = wm + ri * 16 + q * 4 + reg;
      int r = m0 + ml;
      int lab = labT[ml];
      float s = 0.0f;
#pragma unroll
      for (int ci = 0; ci < 4; ++ci) {
        float cv = acc[ri][ci][reg] * iw[ci];
        cv = fminf(fmaxf(cv, -1.0f + EPS_), 1.0f - EPS_);
        float logit = cv;
        if (vcol[ci] == lab) {
          logit = cv * COSM - sqrtf(fmaxf(1.0f - cv * cv, 0.0f)) * SINM;
          Lb[r] = logit;               // unique writer across grid
        }
        s += (vcol[ci] < V_) ? __expf(logit) : 0.0f;
      }
      s += __shfl_xor(s, 1, 64);
      s += __shfl_xor(s, 2, 64);
      s += __shfl_xor(s, 4, 64);
      s += __shfl_xor(s, 8, 64);
      if (l15 == 0) atomicAdd(&S[r], s);
    }
  }
}

// ---------------------------------------------------------------------------
// Kernel 2 FALLBACK (verbatim R0 best): inline fp32->bf16 B-path.
// Used only if the workspace is too small for wbT.
// ---------------------------------------------------------------------------
__global__ __launch_bounds__(256) void gemm_fused_inline(
    const unsigned short* __restrict__ xb,
    const float* __restrict__ w,
    const int* __restrict__ labels,
    float* __restrict__ S, float* __restrict__ Lb) {
  int bid = blockIdx.x;
  int xcd = bid & 7;
  int slot = bid >> 3;
  int tn = xcd * 98 + (slot >> 3);
  int tm = slot & 7;
  if (tn >= NT_) return;
  int m0 = tm * BM, n0 = tn * BN;

  __shared__ unsigned short Ab[BM * BK];
  __shared__ unsigned short Bb[BN * BK];
  __shared__ float sqred[8][BN];
  __shared__ float iwL[BN];
  __shared__ int labT[BM];
  int t = threadIdx.x;
  if (t < BM) labT[t] = labels[m0 + t];
  int lane = t & 63;
  int q = lane >> 4, l15 = lane & 15;
  int wave = t >> 6;
  int wm = (wave & 1) * 64, wn = (wave >> 1) * 64;
  f32x4 acc[4][4] = {};

  const unsigned short* gA[4];
  unsigned short* lA[4];
#pragma unroll
  for (int j = 0; j < 4; ++j) {
    int p = t + 256 * j;
    int m = p >> 3;
    int kc = (p & 7) ^ (m & 7);
    gA[j] = xb + (size_t)(m0 + m) * D_ + kc * 8;
    lA[j] = Ab + p * 8;
  }

  int cg = t & 31;
  int rp = t >> 5;
  int c0l = cg * 4;
  bool vok = (n0 + c0l + 3) < V_;
  const float* wbase = w + (size_t)rp * 8 * V_ + n0 + c0l;
  unsigned short* bdst[4];
#pragma unroll
  for (int cc = 0; cc < 4; ++cc) {
    int col = c0l + cc;
    bdst[cc] = &Bb[(col * 8 + (rp ^ (col & 7))) * 8];
  }
  float ssq[4] = {0.0f, 0.0f, 0.0f, 0.0f};

  for (int kt = 0; kt < D_; kt += BK) {
#pragma unroll
    for (int j = 0; j < 4; ++j) async_copy16(lA[j], gA[j] + kt);

    f32x4 row[8];
    if (vok) {
#pragma unroll
      for (int i = 0; i < 8; ++i)
        row[i] = *(const f32x4*)(wbase + (size_t)i * V_);
    } else {
#pragma unroll
      for (int i = 0; i < 8; ++i) row[i] = f32x4{0.0f, 0.0f, 0.0f, 0.0f};
    }
#pragma unroll
    for (int cc = 0; cc < 4; ++cc) {
      US8 pk;
#pragma unroll
      for (int i = 0; i < 8; ++i) {
        float v = row[i][cc];
        ssq[cc] += v * v;
        pk.h[i] = f2bf(v);
      }
      *(US8*)bdst[cc] = pk;
    }
    wbase += (size_t)BK * V_;

    __syncthreads();
    int h = l15 & 7;
#pragma unroll
    for (int s = 0; s < 2; ++s) {
      int kx = s * 4 + q;
      bf16x8 af[4], bfr[4];
#pragma unroll
      for (int ri = 0; ri < 4; ++ri) {
        int row_ = wm + ri * 16 + l15;
        af[ri] = *(const bf16x8*)&Ab[(row_ * 8 + (kx ^ h)) * 8];
      }
#pragma unroll
      for (int ci = 0; ci < 4; ++ci) {
        int row_ = wn + ci * 16 + l15;
        bfr[ci] = *(const bf16x8*)&Bb[(row_ * 8 + (kx ^ h)) * 8];
      }
#pragma unroll
      for (int ri = 0; ri < 4; ++ri)
#pragma unroll
        for (int ci = 0; ci < 4; ++ci)
          acc[ri][ci] = __builtin_amdgcn_mfma_f32_16x16x32_bf16(
              af[ri], bfr[ci], acc[ri][ci], 0, 0, 0);
    }
    __syncthreads();
  }

#pragma unroll
  for (int cc = 0; cc < 4; ++cc) sqred[rp][c0l + cc] = ssq[cc];
  __syncthreads();
  if (t < BN) {
    float tot = 0.0f;
#pragma unroll
    for (int p = 0; p < 8; ++p) tot += sqred[p][t];
    iwL[t] = ((n0 + t) < V_) ? 1.0f / fmaxf(sqrtf(tot), 1e-12f) : 0.0f;
  }
  __syncthreads();

  float iw[4]; int vcol[4];
#pragma unroll
  for (int ci = 0; ci < 4; ++ci) {
    int nl = wn + ci * 16 + l15;
    vcol[ci] = n0 + nl;
    iw[ci] = iwL[nl];
  }
#pragma unroll
  for (int ri = 0; ri < 4; ++ri) {
#pragma unroll
    for (int reg = 0; reg < 4; ++reg) {
      int ml = wm + ri * 16 + q * 4 + reg;
      int r = m0 + ml;
      int lab = labT[ml];
      float s = 0.0f;
#pragma unroll
      for (int ci = 0; ci < 4; ++ci) {
        float cv = acc[ri][ci][reg] * iw[ci];
        cv = fminf(fmaxf(cv, -1.0f + EPS_), 1.0f - EPS_);
        float logit = cv;
        if (vcol[ci] == lab) {
          logit = cv * COSM - sqrtf(fmaxf(1.0f - cv * cv, 0.0f)) * SINM;
          Lb[r] = logit;
        }
        s += (vcol[ci] < V_) ? __expf(logit) : 0.0f;
      }
      s += __shfl_xor(s, 1, 64);
      s += __shfl_xor(s, 2, 64);
      s += __shfl_xor(s, 4, 64);
      s += __shfl_xor(s, 8, 64);
      if (l15 == 0) atomicAdd(&S[r], s);
    }
  }
}

// ---------------------------------------------------------------------------
// Kernel 3: loss = mean(log(S) - label_logit)
// ---------------------------------------------------------------------------
__global__ void finalk(const float* __restrict__ S, const float* __restrict__ Lb,
                       float* __restrict__ out) {
  __shared__ float red[256];
  int t = threadIdx.x;
  float s = 0.0f;
  for (int i = t; i < B_; i += 256) s += logf(S[i]) - Lb[i];
  red[t] = s;
  __syncthreads();
  for (int o = 128; o > 0; o >>= 1) {
    if (t < o) red[t] += red[t + o];
    __syncthreads();
  }
  if (t == 0) out[0] = red[0] * (1.0f / B_);
}

// ---------------------------------------------------------------------------
extern "C" void kernel_launch(void* const* d_in, const int* in_sizes, int n_in,
                              void* d_out, int out_size, void* d_ws, size_t ws_size,
                              hipStream_t stream) {
  const float* x = (const float*)d_in[0];
  const float* w = (const float*)d_in[1];
  const int* labels = (const int*)d_in[2];
  float* out = (float*)d_out;
  char* ws = (char*)d_ws;
  // ws layout (16B-aligned):
  //   xb   @ 0        : 1024*512 bf16            = 1,048,576 B
  //   S    @ 1048576  : 1024 f32                 =     4,096 B
  //   Lb   @ 1052672  : 1024 f32                 =     4,096 B
  //   wssq @ 1056768  : 100096 f32               =   400,384 B
  //   wbT  @ 1457152  : 100096*512 bf16 (transp) = 102,498,304 B
  unsigned short* xb = (unsigned short*)ws;
  float* S    = (float*)(ws + 1048576ull);
  float* Lb   = (float*)(ws + 1052672ull);
  float* wssq = (float*)(ws + 1056768ull);
  unsigned short* wbT = (unsigned short*)(ws + 1457152ull);
  const size_t WS_NEED = 1457152ull + (size_t)NP_ * D_ * 2ull;

  x_prep<<<256, 256, 0, stream>>>(x, xb, S);
  if (ws_size >= WS_NEED) {
    w_prep<<<NP_ / WPC, 256, 0, stream>>>(w, wbT, wssq);
    gemm_fused_dma<<<6272, 256, 0, stream>>>(xb, wbT, wssq, labels, S, Lb);
  } else {
    gemm_fused_inline<<<6272, 256, 0, stream>>>(xb, w, labels, S, Lb);
  }
  finalk<<<1, 256, 0, stream>>>(S, Lb, out);
}

// Round 3
// 494.225 us; speedup vs baseline: 1.2592x; 1.0916x over previous
//
#include <hip/hip_runtime.h>
#include <math.h>

// Problem constants
#define B_    1024
#define D_    512
#define V_    100000
#define NP_   100096            // padded V (782 tiles * 128)
#define NT_   782
#define EPS_  1e-7f
#define COSM  0.9210609940028851f   // cos(0.4)
#define SINM  0.3894183423086505f   // sin(0.4)

typedef __bf16 bf16x8 __attribute__((ext_vector_type(8)));
typedef float  f32x4  __attribute__((ext_vector_type(4)));

struct alignas(16) US8 { unsigned short h[8]; };

// round-to-nearest-even float -> bf16 bits (inputs finite)
__device__ __forceinline__ unsigned short f2bf(float f) {
  union { float f; unsigned u; } a; a.f = f;
  unsigned u = a.u;
  u += 0x7FFFu + ((u >> 16) & 1u);
  return (unsigned short)(u >> 16);
}

__device__ __forceinline__ void async_copy16(void* lds, const void* g) {
  __builtin_amdgcn_global_load_lds(
      (const __attribute__((address_space(1))) void*)g,
      (__attribute__((address_space(3))) void*)lds, 16, 0, 0);
}

// ---------------------------------------------------------------------------
// Kernel 1: L2-normalize rows of x -> bf16; zero S.
// grid 256 x block 256 (4 waves = 4 rows per block)
// ---------------------------------------------------------------------------
__global__ void x_prep(const float* __restrict__ x,
                       unsigned short* __restrict__ xb,
                       float* __restrict__ S) {
  int t = threadIdx.x;
  int lane = t & 63, wave = t >> 6;
  int row = blockIdx.x * 4 + wave;
  const float* xr = x + (size_t)row * D_;
  f32x4 a = *(const f32x4*)(xr + lane * 8);
  f32x4 b = *(const f32x4*)(xr + lane * 8 + 4);
  float ss = a[0]*a[0] + a[1]*a[1] + a[2]*a[2] + a[3]*a[3]
           + b[0]*b[0] + b[1]*b[1] + b[2]*b[2] + b[3]*b[3];
#pragma unroll
  for (int off = 32; off > 0; off >>= 1) ss += __shfl_xor(ss, off, 64);
  float inv = 1.0f / fmaxf(sqrtf(ss), 1e-12f);
  US8 pk;
#pragma unroll
  for (int j = 0; j < 4; ++j) pk.h[j]     = f2bf(a[j] * inv);
#pragma unroll
  for (int j = 0; j < 4; ++j) pk.h[4 + j] = f2bf(b[j] * inv);
  *(US8*)(xb + (size_t)row * D_ + lane * 8) = pk;
  if (lane == 0) S[row] = 0.0f;
}

// ---------------------------------------------------------------------------
// Kernel 1b (v3): w fp32 [D][V] -> bf16 transposed wbT [NP][D] via LDS
// transpose at 16B granularity BOTH ways, conflict-free swizzle
// (physical chunk = kc ^ (col>>2); verified: phase-1 writes and phase-2
// reads each cover all 8 bank-groups per instruction).
// Thread assembles US8 in registers (8 rows x 4 cols) -> ds_write_b128.
// Per-column ssq block-complete -> direct wssq store. grid 1564 x 256.
// ---------------------------------------------------------------------------
#define WPC 64
#define KH  256

__global__ __launch_bounds__(256) void w_prep(const float* __restrict__ w,
                                              unsigned short* __restrict__ wbT,
                                              float* __restrict__ wssq) {
  __shared__ US8  T16[WPC][32];   // 32 KB (64 cols x 32 chunks of 16B)
  __shared__ float sq[16][WPC];   // 4 KB
  int t = threadIdx.x;
  int c0 = blockIdx.x * WPC;
  int qv = t & 15;                // column quad
  int rg = t >> 4;                // 0..15
  int colv = qv * 4;
  int lane = t & 63, wave = t >> 6;
  bool vok = (c0 + colv + 3) < V_;   // all-or-nothing (V_ % 4 == 0)
  float ssq[4] = {0.0f, 0.0f, 0.0f, 0.0f};

  for (int h = 0; h < 2; ++h) {
    // ---- phase 1: coalesced read, convert, reg-assemble, b128 LDS write
#pragma unroll
    for (int o = 0; o < 2; ++o) {
      int kc = rg * 2 + o;               // k-chunk 0..31 within half
      int rowb = h * KH + kc * 8;
      US8 pk[4] = {};
      if (vok) {
#pragma unroll
        for (int i = 0; i < 8; ++i) {
          f32x4 v = *(const f32x4*)(w + (size_t)(rowb + i) * V_ + c0 + colv);
#pragma unroll
          for (int cc = 0; cc < 4; ++cc) {
            ssq[cc] += v[cc] * v[cc];
            pk[cc].h[i] = f2bf(v[cc]);
          }
        }
      }
#pragma unroll
      for (int cc = 0; cc < 4; ++cc)
        T16[colv + cc][kc ^ qv] = pk[cc];     // col>>2 == qv for this quad
    }
    __syncthreads();
    // ---- phase 2: conflict-free LDS read, coalesced 512B-per-col stores
#pragma unroll
    for (int ci = 0; ci < 8; ++ci) {
      int col = wave * 16 + ci * 2 + (lane >> 5);
      int kc = lane & 31;
      US8 pk = T16[col][kc ^ (col >> 2)];
      *(US8*)(wbT + (size_t)(c0 + col) * D_ + h * KH + kc * 8) = pk;
    }
    __syncthreads();   // T16 reused next half
  }

  // ---- column sum-of-squares: block-local reduce, direct store
#pragma unroll
  for (int cc = 0; cc < 4; ++cc) sq[rg][colv + cc] = ssq[cc];
  __syncthreads();
  if (t < WPC && (c0 + t) < V_) {
    float tot = 0.0f;
#pragma unroll
    for (int p = 0; p < 16; ++p) tot += sq[p][t];
    wssq[c0 + t] = tot;
  }
}

// ---------------------------------------------------------------------------
// Kernel 2 (v3): BM=256 x BN=128 bf16 MFMA GEMM, 512 threads / 8 waves
// (wave grid 4m x 2n, per-wave 64x64 = proven acc/epilogue code).
// Single-buffered (R2 showed dbuf hurts: occupancy > explicit pipelining).
// 48KB LDS + VGPR<=128 -> 2 blocks/CU. The 4 tm-blocks of each tn share
// an XCD so the wbT slice L2-hits. Fused ArcFace epilogue.
// grid 3136 x block 512.
// ---------------------------------------------------------------------------
#define BM 256
#define BN 128
#define BK 64
#define NKT (D_ / BK)

__global__ __launch_bounds__(512, 4) void gemm_fused_dma(
    const unsigned short* __restrict__ xb,
    const unsigned short* __restrict__ wbT,
    const float* __restrict__ wssq,
    const int* __restrict__ labels,
    float* __restrict__ S, float* __restrict__ Lb) {
  int bid = blockIdx.x;
  int xcd = bid & 7;
  int slot = bid >> 3;          // 0..391
  int tm = slot & 3;
  int tn = xcd * 98 + (slot >> 2);
  if (tn >= NT_) return;
  int m0 = tm * BM, n0 = tn * BN;

  // LDS slot p (16B chunks) holds (m = p>>3, kc = (p&7) ^ (m&7))
  __shared__ unsigned short Ab[BM * BK];  // 32 KB
  __shared__ unsigned short Bb[BN * BK];  // 16 KB
  __shared__ int labT[BM];                // 1 KB
  int t = threadIdx.x;
  if (t < BM) labT[t] = labels[m0 + t];
  int lane = t & 63;
  int q = lane >> 4, l15 = lane & 15;
  int wave = t >> 6;                      // 0..7
  int wm = (wave & 3) * 64, wn = (wave >> 2) * 64;
  f32x4 acc[4][4] = {};

  // ---- staging addresses: pre-swizzled global src, linear LDS dest ----
  const unsigned short* gA[4]; unsigned short* lA[4];
  const unsigned short* gB[2]; unsigned short* lB[2];
#pragma unroll
  for (int j = 0; j < 4; ++j) {
    int p = t + 512 * j;                  // 0..2047
    int m = p >> 3;
    int kc = (p & 7) ^ (m & 7);
    gA[j] = xb + (size_t)(m0 + m) * D_ + kc * 8;
    lA[j] = Ab + p * 8;
  }
#pragma unroll
  for (int j = 0; j < 2; ++j) {
    int p = t + 512 * j;                  // 0..1023
    int m = p >> 3;
    int kc = (p & 7) ^ (m & 7);
    gB[j] = wbT + (size_t)(n0 + m) * D_ + kc * 8;   // wbT is [col][K]
    lB[j] = Bb + p * 8;
  }

  int h = l15 & 7;
  for (int kt = 0; kt < D_; kt += BK) {
#pragma unroll
    for (int j = 0; j < 4; ++j) async_copy16(lA[j], gA[j] + kt);
#pragma unroll
    for (int j = 0; j < 2; ++j) async_copy16(lB[j], gB[j] + kt);
    __syncthreads();            // drains vmcnt before s_barrier

#pragma unroll
    for (int s = 0; s < 2; ++s) {
      int kx = s * 4 + q;
      bf16x8 af[4], bfr[4];
#pragma unroll
      for (int ri = 0; ri < 4; ++ri) {
        int row_ = wm + ri * 16 + l15;
        af[ri] = *(const bf16x8*)&Ab[(row_ * 8 + (kx ^ h)) * 8];
      }
#pragma unroll
      for (int ci = 0; ci < 4; ++ci) {
        int row_ = wn + ci * 16 + l15;
        bfr[ci] = *(const bf16x8*)&Bb[(row_ * 8 + (kx ^ h)) * 8];
      }
#pragma unroll
      for (int ri = 0; ri < 4; ++ri)
#pragma unroll
        for (int ci = 0; ci < 4; ++ci)
          acc[ri][ci] = __builtin_amdgcn_mfma_f32_16x16x32_bf16(
              af[ri], bfr[ci], acc[ri][ci], 0, 0, 0);
    }
    __syncthreads();
  }

  // ---- epilogue: C/D layout col = lane&15 (n side), row = q*4 + reg ----
  float iw[4]; int vcol[4];
#pragma unroll
  for (int ci = 0; ci < 4; ++ci) {
    int nl = wn + ci * 16 + l15;
    vcol[ci] = n0 + nl;
    iw[ci] = (vcol[ci] < V_) ? 1.0f / fmaxf(sqrtf(wssq[vcol[ci]]), 1e-12f)
                             : 0.0f;
  }
#pragma unroll
  for (int ri = 0; ri < 4; ++ri) {
#pragma unroll
    for (int reg = 0; reg < 4; ++reg) {
      int ml = wm + ri * 16 + q * 4 + reg;
      int r = m0 + ml;
      int lab = labT[ml];
      float s = 0.0f;
#pragma unroll
      for (int ci = 0; ci < 4; ++ci) {
        float cv = acc[ri][ci][reg] * iw[ci];
        cv = fminf(fmaxf(cv, -1.0f + EPS_), 1.0f - EPS_);
        float logit = cv;
        if (vcol[ci] == lab) {
          logit = cv * COSM - sqrtf(fmaxf(1.0f - cv * cv, 0.0f)) * SINM;
          Lb[r] = logit;               // unique writer across grid
        }
        s += (vcol[ci] < V_) ? __expf(logit) : 0.0f;
      }
      s += __shfl_xor(s, 1, 64);
      s += __shfl_xor(s, 2, 64);
      s += __shfl_xor(s, 4, 64);
      s += __shfl_xor(s, 8, 64);
      if (l15 == 0) atomicAdd(&S[r], s);
    }
  }
}

// ---------------------------------------------------------------------------
// Kernel 2 FALLBACK (verbatim R0 best, own 128x128x64 constants): inline
// fp32->bf16 B-path. Used only if the workspace is too small for wbT.
// ---------------------------------------------------------------------------
__global__ __launch_bounds__(256) void gemm_fused_inline(
    const unsigned short* __restrict__ xb,
    const float* __restrict__ w,
    const int* __restrict__ labels,
    float* __restrict__ S, float* __restrict__ Lb) {
  int bid = blockIdx.x;
  int xcd = bid & 7;
  int slot = bid >> 3;
  int tn = xcd * 98 + (slot >> 3);
  int tm = slot & 7;
  if (tn >= NT_) return;
  int m0 = tm * 128, n0 = tn * 128;

  __shared__ unsigned short Ab[128 * 64];
  __shared__ unsigned short Bb[128 * 64];
  __shared__ float sqred[8][128];
  __shared__ float iwL[128];
  __shared__ int labT[128];
  int t = threadIdx.x;
  if (t < 128) labT[t] = labels[m0 + t];
  int lane = t & 63;
  int q = lane >> 4, l15 = lane & 15;
  int wave = t >> 6;
  int wm = (wave & 1) * 64, wn = (wave >> 1) * 64;
  f32x4 acc[4][4] = {};

  const unsigned short* gA[4];
  unsigned short* lA[4];
#pragma unroll
  for (int j = 0; j < 4; ++j) {
    int p = t + 256 * j;
    int m = p >> 3;
    int kc = (p & 7) ^ (m & 7);
    gA[j] = xb + (size_t)(m0 + m) * D_ + kc * 8;
    lA[j] = Ab + p * 8;
  }

  int cg = t & 31;
  int rp = t >> 5;
  int c0l = cg * 4;
  bool vok = (n0 + c0l + 3) < V_;
  const float* wbase = w + (size_t)rp * 8 * V_ + n0 + c0l;
  unsigned short* bdst[4];
#pragma unroll
  for (int cc = 0; cc < 4; ++cc) {
    int col = c0l + cc;
    bdst[cc] = &Bb[(col * 8 + (rp ^ (col & 7))) * 8];
  }
  float ssq[4] = {0.0f, 0.0f, 0.0f, 0.0f};

  for (int kt = 0; kt < D_; kt += 64) {
#pragma unroll
    for (int j = 0; j < 4; ++j) async_copy16(lA[j], gA[j] + kt);

    f32x4 row[8];
    if (vok) {
#pragma unroll
      for (int i = 0; i < 8; ++i)
        row[i] = *(const f32x4*)(wbase + (size_t)i * V_);
    } else {
#pragma unroll
      for (int i = 0; i < 8; ++i) row[i] = f32x4{0.0f, 0.0f, 0.0f, 0.0f};
    }
#pragma unroll
    for (int cc = 0; cc < 4; ++cc) {
      US8 pk;
#pragma unroll
      for (int i = 0; i < 8; ++i) {
        float v = row[i][cc];
        ssq[cc] += v * v;
        pk.h[i] = f2bf(v);
      }
      *(US8*)bdst[cc] = pk;
    }
    wbase += (size_t)64 * V_;

    __syncthreads();
    int h = l15 & 7;
#pragma unroll
    for (int s = 0; s < 2; ++s) {
      int kx = s * 4 + q;
      bf16x8 af[4], bfr[4];
#pragma unroll
      for (int ri = 0; ri < 4; ++ri) {
        int row_ = wm + ri * 16 + l15;
        af[ri] = *(const bf16x8*)&Ab[(row_ * 8 + (kx ^ h)) * 8];
      }
#pragma unroll
      for (int ci = 0; ci < 4; ++ci) {
        int row_ = wn + ci * 16 + l15;
        bfr[ci] = *(const bf16x8*)&Bb[(row_ * 8 + (kx ^ h)) * 8];
      }
#pragma unroll
      for (int ri = 0; ri < 4; ++ri)
#pragma unroll
        for (int ci = 0; ci < 4; ++ci)
          acc[ri][ci] = __builtin_amdgcn_mfma_f32_16x16x32_bf16(
              af[ri], bfr[ci], acc[ri][ci], 0, 0, 0);
    }
    __syncthreads();
  }

#pragma unroll
  for (int cc = 0; cc < 4; ++cc) sqred[rp][c0l + cc] = ssq[cc];
  __syncthreads();
  if (t < 128) {
    float tot = 0.0f;
#pragma unroll
    for (int p = 0; p < 8; ++p) tot += sqred[p][t];
    iwL[t] = ((n0 + t) < V_) ? 1.0f / fmaxf(sqrtf(tot), 1e-12f) : 0.0f;
  }
  __syncthreads();

  float iw[4]; int vcol[4];
#pragma unroll
  for (int ci = 0; ci < 4; ++ci) {
    int nl = wn + ci * 16 + l15;
    vcol[ci] = n0 + nl;
    iw[ci] = iwL[nl];
  }
#pragma unroll
  for (int ri = 0; ri < 4; ++ri) {
#pragma unroll
    for (int reg = 0; reg < 4; ++reg) {
      int ml = wm + ri * 16 + q * 4 + reg;
      int r = m0 + ml;
      int lab = labT[ml];
      float s = 0.0f;
#pragma unroll
      for (int ci = 0; ci < 4; ++ci) {
        float cv = acc[ri][ci][reg] * iw[ci];
        cv = fminf(fmaxf(cv, -1.0f + EPS_), 1.0f - EPS_);
        float logit = cv;
        if (vcol[ci] == lab) {
          logit = cv * COSM - sqrtf(fmaxf(1.0f - cv * cv, 0.0f)) * SINM;
          Lb[r] = logit;
        }
        s += (vcol[ci] < V_) ? __expf(logit) : 0.0f;
      }
      s += __shfl_xor(s, 1, 64);
      s += __shfl_xor(s, 2, 64);
      s += __shfl_xor(s, 4, 64);
      s += __shfl_xor(s, 8, 64);
      if (l15 == 0) atomicAdd(&S[r], s);
    }
  }
}

// ---------------------------------------------------------------------------
// Kernel 3: loss = mean(log(S) - label_logit)
// ---------------------------------------------------------------------------
__global__ void finalk(const float* __restrict__ S, const float* __restrict__ Lb,
                       float* __restrict__ out) {
  __shared__ float red[256];
  int t = threadIdx.x;
  float s = 0.0f;
  for (int i = t; i < B_; i += 256) s += logf(S[i]) - Lb[i];
  red[t] = s;
  __syncthreads();
  for (int o = 128; o > 0; o >>= 1) {
    if (t < o) red[t] += red[t + o];
    __syncthreads();
  }
  if (t == 0) out[0] = red[0] * (1.0f / B_);
}

// ---------------------------------------------------------------------------
extern "C" void kernel_launch(void* const* d_in, const int* in_sizes, int n_in,
                              void* d_out, int out_size, void* d_ws, size_t ws_size,
                              hipStream_t stream) {
  const float* x = (const float*)d_in[0];
  const float* w = (const float*)d_in[1];
  const int* labels = (const int*)d_in[2];
  float* out = (float*)d_out;
  char* ws = (char*)d_ws;
  // ws layout (16B-aligned):
  //   xb   @ 0        : 1024*512 bf16            = 1,048,576 B
  //   S    @ 1048576  : 1024 f32                 =     4,096 B
  //   Lb   @ 1052672  : 1024 f32                 =     4,096 B
  //   wssq @ 1056768  : 100096 f32               =   400,384 B
  //   wbT  @ 1457152  : 100096*512 bf16 (transp) = 102,498,304 B
  unsigned short* xb = (unsigned short*)ws;
  float* S    = (float*)(ws + 1048576ull);
  float* Lb   = (float*)(ws + 1052672ull);
  float* wssq = (float*)(ws + 1056768ull);
  unsigned short* wbT = (unsigned short*)(ws + 1457152ull);
  const size_t WS_NEED = 1457152ull + (size_t)NP_ * D_ * 2ull;

  x_prep<<<256, 256, 0, stream>>>(x, xb, S);
  if (ws_size >= WS_NEED) {
    w_prep<<<NP_ / WPC, 256, 0, stream>>>(w, wbT, wssq);
    gemm_fused_dma<<<3136, 512, 0, stream>>>(xb, wbT, wssq, labels, S, Lb);
  } else {
    gemm_fused_inline<<<6272, 256, 0, stream>>>(xb, w, labels, S, Lb);
  }
  finalk<<<1, 256, 0, stream>>>(S, Lb, out);
}